// Round 7
// baseline (923.630 us; speedup 1.0000x reference)
//
#include <hip/hip_runtime.h>

// AdaIN on MI355X — 4-dispatch pipeline.
// content: (Nc=1e6, C=64) f32, style: (Ns=2.5e5, C=64) f32, B=16 segments.
// R6 lesson: register-accumulator switch was if-converted -> 64 VALU/row,
// VALU-bound at 49%. R7: block-shared LDS accumulator with ds_add_f32,
// conflict-free layout (addr = b*64+lane -> 2 lanes/bank = free), one row
// per wave, O(1) VALU per row. memset ws -> reduce -> finalize -> apply.

#define NB 16          // num_batches
#define NC 64          // channels (== wavefront size)
#define NREP 16        // global partial-buffer replicas
#define CBLKS 1638     // content-reduce blocks  } total 2048 = 8 blocks/CU,
#define SBLKS 410      // style-reduce blocks    } one full residency round

typedef float fvec4 __attribute__((ext_vector_type(4)));   // nontemporal-ok

// ws float layout:
#define WS_CPART 0                        // NREP * 2048 (sum[1024], sumsq[1024])
#define WS_SPART (NREP * 2048)            // NREP * 2048
#define WS_CCNT  (2 * NREP * 2048)        // NREP * 16
#define WS_SCNT  (WS_CCNT + NREP * NB)    // NREP * 16
#define WS_SCALE (WS_SCNT + NREP * NB)    // 1024
#define WS_BIAS  (WS_SCALE + 1024)        // 1024
#define WS_ZERO_FLOATS WS_SCALE

__device__ __forceinline__ void lds_add(float* p, float v)
{
    // workgroup-scope relaxed fp add -> ds_add_f32 (native LDS float atomic)
    __hip_atomic_fetch_add(p, v, __ATOMIC_RELAXED, __HIP_MEMORY_SCOPE_WORKGROUP);
}

__device__ __forceinline__ void reduce_body(
    const float* __restrict__ feats, const int* __restrict__ idx, int n,
    float* __restrict__ part, float* __restrict__ cntp,
    int blk, int nblk, int tid, float* acc /*2048 floats: sum[16][64], sq +1024*/)
{
    const int lane = tid & 63;
    const int wv   = tid >> 6;

    // zero the block-shared accumulator
    for (int i = tid; i < 2048; i += 256) acc[i] = 0.f;
    __syncthreads();

    const int W  = nblk * 4;               // waves in this group
    const int w  = blk * 4 + wv;
    const int L  = (n + W - 1) / W;        // contiguous rows per wave
    const int r0 = w * L;
    const int r1 = (r0 + L < n) ? (r0 + L) : n;

    float cnt = 0.f;                        // lane b holds count of batch b
    float* accs = acc;                      // sum  [b*64+lane]
    float* accq = acc + 1024;               // sumsq[b*64+lane]

    int rc = r0;
    // fast path: 16 rows per iteration; idx via one coalesced load + readlane
    for (; rc + 16 <= r1; rc += 16) {
        const int vidx = idx[rc + (lane & 15)];      // lanes 0..15 carry rows
        const float* ps = feats + (size_t)rc * NC + lane;
        float val[16];
        #pragma unroll
        for (int j = 0; j < 16; ++j) val[j] = ps[j * NC];   // const offsets
        #pragma unroll
        for (int j = 0; j < 16; ++j) {
            const int b = __builtin_amdgcn_readlane(vidx, j);   // SGPR batch
            lds_add(&accs[b * NC + lane], val[j]);
            lds_add(&accq[b * NC + lane], val[j] * val[j]);
            cnt += (lane == b) ? 1.f : 0.f;
        }
    }
    // tail rows
    for (; rc < r1; ++rc) {
        const float v = feats[(size_t)rc * NC + lane];
        const int  b = __builtin_amdgcn_readfirstlane(idx[rc]);
        lds_add(&accs[b * NC + lane], v);
        lds_add(&accq[b * NC + lane], v * v);
        cnt += (lane == b) ? 1.f : 0.f;
    }

    __syncthreads();
    // flush block accumulator into this block's global replica
    float* dst = part + (blk & (NREP - 1)) * 2048;
    for (int i = tid; i < 2048; i += 256)
        atomicAdd(&dst[i], acc[i]);
    if (lane < NB)
        atomicAdd(&cntp[(blk & (NREP - 1)) * NB + lane], cnt);
}

__global__ __launch_bounds__(256) void reduce_stats(
    const float* __restrict__ content, const int* __restrict__ ci, int Nc,
    const float* __restrict__ style,   const int* __restrict__ si, int Ns,
    float* __restrict__ ws)
{
    __shared__ float acc[2048];            // 8 KB
    if (blockIdx.x < CBLKS)
        reduce_body(content, ci, Nc, ws + WS_CPART, ws + WS_CCNT,
                    blockIdx.x, CBLKS, threadIdx.x, acc);
    else
        reduce_body(style, si, Ns, ws + WS_SPART, ws + WS_SCNT,
                    blockIdx.x - CBLKS, SBLKS, threadIdx.x, acc);
}

__global__ void finalize_kernel(float* __restrict__ ws)
{
    if (threadIdx.x >= NC) return;
    const int c = threadIdx.x;
    const float* c_part = ws + WS_CPART;
    const float* s_part = ws + WS_SPART;
    const float* c_cntp = ws + WS_CCNT;
    const float* s_cntp = ws + WS_SCNT;
    float* scale = ws + WS_SCALE;
    float* bias  = ws + WS_BIAS;

    float gm = 0.f, gs = 0.f;
    for (int b = 0; b < NB; ++b) {
        float csum = 0.f, csq = 0.f, ssum = 0.f, ssq = 0.f, ccnt = 0.f, scnt = 0.f;
        #pragma unroll
        for (int rep = 0; rep < NREP; ++rep) {
            csum += c_part[rep * 2048 + b * NC + c];
            csq  += c_part[rep * 2048 + 1024 + b * NC + c];
            ssum += s_part[rep * 2048 + b * NC + c];
            ssq  += s_part[rep * 2048 + 1024 + b * NC + c];
            ccnt += c_cntp[rep * NB + b];
            scnt += s_cntp[rep * NB + b];
        }
        const float smean = ssum / scnt;
        const float svar  = (ssq - scnt * smean * smean) / (scnt - 1.0f);
        const float sstd  = sqrtf(fmaxf(svar, 0.f)) + 1e-8f;
        if (b == 0) { gm = smean; gs = sstd; }
        else        { gm = 0.9f * gm + 0.1f * smean; gs = 0.9f * gs + 0.1f * sstd; }
        const float cmean = csum / ccnt;
        const float cvar  = (csq - ccnt * cmean * cmean) / (ccnt - 1.0f);
        const float cstd  = sqrtf(fmaxf(cvar, 0.f)) + 1e-8f;
        const float sc = gs / cstd;        // out = sc*x + bi
        scale[b * NC + c] = sc;
        bias [b * NC + c] = gm - sc * cmean;
    }
}

__global__ __launch_bounds__(256) void apply_kernel(
    const float* __restrict__ content, const int* __restrict__ ci, int Nc,
    const float* __restrict__ ws, fvec4* __restrict__ out4)
{
    __shared__ fvec4 s_sc[NB * 17];        // stride-17 pad
    __shared__ fvec4 s_bi[NB * 17];
    const fvec4* scale4 = (const fvec4*)(ws + WS_SCALE);
    const fvec4* bias4  = (const fvec4*)(ws + WS_BIAS);
    for (int i = threadIdx.x; i < NB * 16; i += 256) {
        const int b = i >> 4, c4 = i & 15;
        s_sc[b * 17 + c4] = scale4[i];
        s_bi[b * 17 + c4] = bias4[i];
    }
    __syncthreads();

    const fvec4* feats4 = (const fvec4*)content;
    const int total4 = Nc * 16;
    const int stride = gridDim.x * 256;
    for (int i = blockIdx.x * 256 + threadIdx.x; i < total4; i += stride) {
        const int r  = i >> 4;
        const int c4 = i & 15;
        const int b  = ci[r];
        const fvec4 v  = feats4[i];
        const fvec4 sc = s_sc[b * 17 + c4];
        const fvec4 bi = s_bi[b * 17 + c4];
        fvec4 o;
        o.x = fmaf(sc.x, v.x, bi.x);
        o.y = fmaf(sc.y, v.y, bi.y);
        o.z = fmaf(sc.z, v.z, bi.z);
        o.w = fmaf(sc.w, v.w, bi.w);
        __builtin_nontemporal_store(o, &out4[i]);
    }
}

extern "C" void kernel_launch(void* const* d_in, const int* in_sizes, int n_in,
                              void* d_out, int out_size, void* d_ws, size_t ws_size,
                              hipStream_t stream)
{
    const float* content = (const float*)d_in[0];
    const float* style   = (const float*)d_in[1];
    const int*   ci      = (const int*)d_in[2];
    const int*   si      = (const int*)d_in[3];

    const int Nc = in_sizes[0] / NC;   // 1,000,000
    const int Ns = in_sizes[1] / NC;   //   250,000

    float* ws = (float*)d_ws;
    // ws never re-poisoned between replays: zero accumulators every call.
    (void)hipMemsetAsync(ws, 0, WS_ZERO_FLOATS * sizeof(float), stream);

    reduce_stats<<<CBLKS + SBLKS, 256, 0, stream>>>(content, ci, Nc, style, si, Ns, ws);
    finalize_kernel<<<1, 64, 0, stream>>>(ws);
    apply_kernel<<<2048, 256, 0, stream>>>(content, ci, Nc, ws, (fvec4*)d_out);
}

// Round 8
// 201.291 us; speedup vs baseline: 4.5885x; 4.5885x over previous
//
#include <hip/hip_runtime.h>

// AdaIN on MI355X — 4-dispatch pipeline.
// content: (Nc=1e6, C=64) f32, style: (Ns=2.5e5, C=64) f32, B=16 segments.
// Reduce history: LDS atomics ~200cyc/wave-instr (R1,R7 both) = dead end;
// if-converted switch = 80 VALU/row, VALU-bound 143us (R6). R8: force REAL
// scalar branches (b is wave-uniform SGPR) with asm-opaque case bodies ->
// 2 VALU + ~5 SALU per row, memory-bound.
// memset ws -> reduce -> finalize -> apply.

#define NB 16          // num_batches
#define NC 64          // channels (== wavefront size)
#define NREP 16        // global partial-buffer replicas
#define CBLKS 2048     // content-reduce blocks (8192 waves, L=123)
#define SBLKS 512      // style-reduce blocks   (2048 waves, L=123)

typedef float fvec4 __attribute__((ext_vector_type(4)));   // nontemporal-ok

// ws float layout:
#define WS_CPART 0                        // NREP * 2048 (sum[1024], sumsq[1024])
#define WS_SPART (NREP * 2048)            // NREP * 2048
#define WS_CCNT  (2 * NREP * 2048)        // NREP * 16
#define WS_SCNT  (WS_CCNT + NREP * NB)    // NREP * 16
#define WS_SCALE (WS_SCNT + NREP * NB)    // 1024
#define WS_BIAS  (WS_SCALE + 1024)        // 1024
#define WS_ZERO_FLOATS WS_SCALE

// Case body opaque to if-conversion: the asm can't be speculated/predicated,
// so the compiler must emit a real scalar branch tree on the SGPR b.
#define DOCASE(k) do { \
    s[k] += v; q[k] = fmaf(v, v, q[k]); \
    asm volatile("" : "+v"(s[k]), "+v"(q[k])); \
} while (0)

__device__ __forceinline__ void accb(int b, float v, float* s, float* q)
{
    if (b < 8) {
        if (b < 4) {
            if (b < 2) { if (b == 0) DOCASE(0);  else DOCASE(1); }
            else       { if (b == 2) DOCASE(2);  else DOCASE(3); }
        } else {
            if (b < 6) { if (b == 4) DOCASE(4);  else DOCASE(5); }
            else       { if (b == 6) DOCASE(6);  else DOCASE(7); }
        }
    } else {
        if (b < 12) {
            if (b < 10) { if (b == 8)  DOCASE(8);  else DOCASE(9);  }
            else        { if (b == 10) DOCASE(10); else DOCASE(11); }
        } else {
            if (b < 14) { if (b == 12) DOCASE(12); else DOCASE(13); }
            else        { if (b == 14) DOCASE(14); else DOCASE(15); }
        }
    }
}

__device__ __forceinline__ void reduce_body(
    const float* __restrict__ feats, const int* __restrict__ idx, int n,
    float* __restrict__ part, float* __restrict__ cntp,
    int blk, int nblk, int tid, float* red /*4*NB*NC LDS*/)
{
    const int lane = tid & 63;
    const int wv   = tid >> 6;

    const int W  = nblk * 4;               // waves in this group
    const int w  = blk * 4 + wv;
    const int L  = (n + W - 1) / W;        // contiguous rows per wave
    const int r0 = w * L;
    const int r1 = (r0 + L < n) ? (r0 + L) : n;

    float s[NB], q[NB];
    #pragma unroll
    for (int k = 0; k < NB; ++k) { s[k] = 0.f; q[k] = 0.f; }
    float cnt = 0.f;                        // lane b holds count of batch b

    int rc = r0;
    const float* p = feats + (size_t)r0 * NC + lane;
    // 8 rows per iteration: one coalesced idx load (lanes 0..7) + 8
    // constant-offset value loads, then 8 branch-tree accumulations.
    for (; rc + 8 <= r1; rc += 8, p += 8 * NC) {
        const int vidx = idx[rc + (lane & 7)];
        float val[8];
        #pragma unroll
        for (int j = 0; j < 8; ++j) val[j] = p[j * NC];
        #pragma unroll
        for (int j = 0; j < 8; ++j) {
            const int b = __builtin_amdgcn_readlane(vidx, j);   // SGPR
            const float v = val[j];
            accb(b, v, s, q);
            cnt += (lane == b) ? 1.f : 0.f;
        }
    }
    for (; rc < r1; ++rc, p += NC) {
        const float v = p[0];
        const int  b = __builtin_amdgcn_readfirstlane(idx[rc]);
        accb(b, v, s, q);
        cnt += (lane == b) ? 1.f : 0.f;
    }

    // Cross-wave reduce in LDS (two phases reuse the buffer), then one
    // atomicAdd per (b,c) per block into this block's replica.
    float* dst = part + (blk & (NREP - 1)) * 2048;

    #pragma unroll
    for (int k = 0; k < NB; ++k) red[wv * 1024 + k * NC + lane] = s[k];
    __syncthreads();
    for (int i = tid; i < NB * NC; i += 256)
        atomicAdd(&dst[i], red[i] + red[1024 + i] + red[2048 + i] + red[3072 + i]);
    __syncthreads();
    #pragma unroll
    for (int k = 0; k < NB; ++k) red[wv * 1024 + k * NC + lane] = q[k];
    __syncthreads();
    for (int i = tid; i < NB * NC; i += 256)
        atomicAdd(&dst[1024 + i], red[i] + red[1024 + i] + red[2048 + i] + red[3072 + i]);

    if (lane < NB)
        atomicAdd(&cntp[(blk & (NREP - 1)) * NB + lane], cnt);
}

__global__ __launch_bounds__(256) void reduce_stats(
    const float* __restrict__ content, const int* __restrict__ ci, int Nc,
    const float* __restrict__ style,   const int* __restrict__ si, int Ns,
    float* __restrict__ ws)
{
    __shared__ float red[4 * NB * NC];     // 16 KB
    if (blockIdx.x < CBLKS)
        reduce_body(content, ci, Nc, ws + WS_CPART, ws + WS_CCNT,
                    blockIdx.x, CBLKS, threadIdx.x, red);
    else
        reduce_body(style, si, Ns, ws + WS_SPART, ws + WS_SCNT,
                    blockIdx.x - CBLKS, SBLKS, threadIdx.x, red);
}

__global__ void finalize_kernel(float* __restrict__ ws)
{
    if (threadIdx.x >= NC) return;
    const int c = threadIdx.x;
    const float* c_part = ws + WS_CPART;
    const float* s_part = ws + WS_SPART;
    const float* c_cntp = ws + WS_CCNT;
    const float* s_cntp = ws + WS_SCNT;
    float* scale = ws + WS_SCALE;
    float* bias  = ws + WS_BIAS;

    float gm = 0.f, gs = 0.f;
    for (int b = 0; b < NB; ++b) {
        float csum = 0.f, csq = 0.f, ssum = 0.f, ssq = 0.f, ccnt = 0.f, scnt = 0.f;
        #pragma unroll
        for (int rep = 0; rep < NREP; ++rep) {
            csum += c_part[rep * 2048 + b * NC + c];
            csq  += c_part[rep * 2048 + 1024 + b * NC + c];
            ssum += s_part[rep * 2048 + b * NC + c];
            ssq  += s_part[rep * 2048 + 1024 + b * NC + c];
            ccnt += c_cntp[rep * NB + b];
            scnt += s_cntp[rep * NB + b];
        }
        const float smean = ssum / scnt;
        const float svar  = (ssq - scnt * smean * smean) / (scnt - 1.0f);
        const float sstd  = sqrtf(fmaxf(svar, 0.f)) + 1e-8f;
        if (b == 0) { gm = smean; gs = sstd; }
        else        { gm = 0.9f * gm + 0.1f * smean; gs = 0.9f * gs + 0.1f * sstd; }
        const float cmean = csum / ccnt;
        const float cvar  = (csq - ccnt * cmean * cmean) / (ccnt - 1.0f);
        const float cstd  = sqrtf(fmaxf(cvar, 0.f)) + 1e-8f;
        const float sc = gs / cstd;        // out = sc*x + bi
        scale[b * NC + c] = sc;
        bias [b * NC + c] = gm - sc * cmean;
    }
}

__global__ __launch_bounds__(256) void apply_kernel(
    const float* __restrict__ content, const int* __restrict__ ci, int Nc,
    const float* __restrict__ ws, fvec4* __restrict__ out4)
{
    __shared__ fvec4 s_sc[NB * 17];        // stride-17 pad
    __shared__ fvec4 s_bi[NB * 17];
    const fvec4* scale4 = (const fvec4*)(ws + WS_SCALE);
    const fvec4* bias4  = (const fvec4*)(ws + WS_BIAS);
    for (int i = threadIdx.x; i < NB * 16; i += 256) {
        const int b = i >> 4, c4 = i & 15;
        s_sc[b * 17 + c4] = scale4[i];
        s_bi[b * 17 + c4] = bias4[i];
    }
    __syncthreads();

    const fvec4* feats4 = (const fvec4*)content;
    const int total4 = Nc * 16;
    const int stride = gridDim.x * 256;
    for (int i = blockIdx.x * 256 + threadIdx.x; i < total4; i += stride) {
        const int r  = i >> 4;
        const int c4 = i & 15;
        const int b  = ci[r];
        const fvec4 v  = feats4[i];
        const fvec4 sc = s_sc[b * 17 + c4];
        const fvec4 bi = s_bi[b * 17 + c4];
        fvec4 o;
        o.x = fmaf(sc.x, v.x, bi.x);
        o.y = fmaf(sc.y, v.y, bi.y);
        o.z = fmaf(sc.z, v.z, bi.z);
        o.w = fmaf(sc.w, v.w, bi.w);
        __builtin_nontemporal_store(o, &out4[i]);
    }
}

extern "C" void kernel_launch(void* const* d_in, const int* in_sizes, int n_in,
                              void* d_out, int out_size, void* d_ws, size_t ws_size,
                              hipStream_t stream)
{
    const float* content = (const float*)d_in[0];
    const float* style   = (const float*)d_in[1];
    const int*   ci      = (const int*)d_in[2];
    const int*   si      = (const int*)d_in[3];

    const int Nc = in_sizes[0] / NC;   // 1,000,000
    const int Ns = in_sizes[1] / NC;   //   250,000

    float* ws = (float*)d_ws;
    // ws never re-poisoned between replays: zero accumulators every call.
    (void)hipMemsetAsync(ws, 0, WS_ZERO_FLOATS * sizeof(float), stream);

    reduce_stats<<<CBLKS + SBLKS, 256, 0, stream>>>(content, ci, Nc, style, si, Ns, ws);
    finalize_kernel<<<1, 64, 0, stream>>>(ws);
    apply_kernel<<<2048, 256, 0, stream>>>(content, ci, Nc, ws, (fvec4*)d_out);
}

// Round 9
// 197.056 us; speedup vs baseline: 4.6871x; 1.0215x over previous
//
#include <hip/hip_runtime.h>

// AdaIN on MI355X — 4-dispatch pipeline.
// content: (Nc=1e6, C=64) f32, style: (Ns=2.5e5, C=64) f32, B=16 segments.
// Reduce history: LDS atomics ~200cyc/wave-instr (R1,R7) dead end; if-converted
// switch 80 VALU/row = 143us (R6); real branch tree ~109us (R8, branch bubbles).
// R9: branch-free address-indexed accumulate — per-wave-private LDS region,
// plain (non-atomic) ds b64 RMW of packed (sum,sq), slot = SGPR b * 512B.
// memset ws -> reduce -> finalize -> apply.

#define NB 16          // num_batches
#define NC 64          // channels (== wavefront size)
#define NREP 16        // global partial-buffer replicas
#define CBLKS 1024     // content-reduce blocks } 1280 total = 5 blocks/CU
#define SBLKS 256      // style-reduce blocks   } (32KB LDS -> 5/CU), L=245

typedef float fvec2 __attribute__((ext_vector_type(2)));
typedef float fvec4 __attribute__((ext_vector_type(4)));   // nontemporal-ok

// ws float layout:
#define WS_CPART 0                        // NREP * 2048 (sum[1024], sumsq[1024])
#define WS_SPART (NREP * 2048)            // NREP * 2048
#define WS_CCNT  (2 * NREP * 2048)        // NREP * 16
#define WS_SCNT  (WS_CCNT + NREP * NB)    // NREP * 16
#define WS_SCALE (WS_SCNT + NREP * NB)    // 1024
#define WS_BIAS  (WS_SCALE + 1024)        // 1024
#define WS_ZERO_FLOATS WS_SCALE

__device__ __forceinline__ void reduce_body(
    const float* __restrict__ feats, const int* __restrict__ idx, int n,
    float* __restrict__ part, float* __restrict__ cntp,
    int blk, int nblk, int tid, fvec2* acc /*[4][NB][NC] = 32 KB*/)
{
    const int lane = tid & 63;
    const int wv   = tid >> 6;

    // zero this wave's private region (no sync needed: wave-local until merge)
    fvec2* myacc = acc + wv * NB * NC;     // [b*64 + lane], 8 B per slot
    #pragma unroll
    for (int k = 0; k < NB; ++k) myacc[k * NC + lane] = fvec2{0.f, 0.f};

    const int W  = nblk * 4;               // waves in this group
    const int w  = blk * 4 + wv;
    const int L  = (n + W - 1) / W;        // contiguous rows per wave
    const int r0 = w * L;
    const int r1 = (r0 + L < n) ? (r0 + L) : n;

    float cnt = 0.f;                        // lane b holds count of batch b

    int rc = r0;
    const float* p = feats + (size_t)r0 * NC + lane;
    // 8 rows per iter: one coalesced idx load (lanes 0..7) + 8 constant-offset
    // row loads; per row a branch-free LDS b64 read-modify-write at slot b.
    for (; rc + 8 <= r1; rc += 8, p += 8 * NC) {
        const int vidx = idx[rc + (lane & 7)];
        float val[8];
        #pragma unroll
        for (int j = 0; j < 8; ++j) val[j] = p[j * NC];
        #pragma unroll
        for (int j = 0; j < 8; ++j) {
            const int b = __builtin_amdgcn_readlane(vidx, j);   // SGPR
            const float v = val[j];
            fvec2 t = myacc[b * NC + lane];        // ds_read_b64
            t.x += v;
            t.y = fmaf(v, v, t.y);
            myacc[b * NC + lane] = t;              // ds_write_b64
            cnt += (lane == b) ? 1.f : 0.f;
        }
    }
    for (; rc < r1; ++rc, p += NC) {
        const float v = p[0];
        const int  b = __builtin_amdgcn_readfirstlane(idx[rc]);
        fvec2 t = myacc[b * NC + lane];
        t.x += v;
        t.y = fmaf(v, v, t.y);
        myacc[b * NC + lane] = t;
        cnt += (lane == b) ? 1.f : 0.f;
    }

    __syncthreads();
    // merge the 4 wave regions, flush to this block's global replica
    float* dst = part + (blk & (NREP - 1)) * 2048;  // sum[1024], sq[1024]
    for (int i = tid; i < NB * NC; i += 256) {
        const fvec2 t = acc[i] + acc[NB * NC + i]
                      + acc[2 * NB * NC + i] + acc[3 * NB * NC + i];
        atomicAdd(&dst[i], t.x);
        atomicAdd(&dst[1024 + i], t.y);
    }
    if (lane < NB)
        atomicAdd(&cntp[(blk & (NREP - 1)) * NB + lane], cnt);
}

__global__ __launch_bounds__(256) void reduce_stats(
    const float* __restrict__ content, const int* __restrict__ ci, int Nc,
    const float* __restrict__ style,   const int* __restrict__ si, int Ns,
    float* __restrict__ ws)
{
    __shared__ fvec2 acc[4 * NB * NC];     // 32 KB
    if (blockIdx.x < CBLKS)
        reduce_body(content, ci, Nc, ws + WS_CPART, ws + WS_CCNT,
                    blockIdx.x, CBLKS, threadIdx.x, acc);
    else
        reduce_body(style, si, Ns, ws + WS_SPART, ws + WS_SCNT,
                    blockIdx.x - CBLKS, SBLKS, threadIdx.x, acc);
}

__global__ void finalize_kernel(float* __restrict__ ws)
{
    if (threadIdx.x >= NC) return;
    const int c = threadIdx.x;
    const float* c_part = ws + WS_CPART;
    const float* s_part = ws + WS_SPART;
    const float* c_cntp = ws + WS_CCNT;
    const float* s_cntp = ws + WS_SCNT;
    float* scale = ws + WS_SCALE;
    float* bias  = ws + WS_BIAS;

    float gm = 0.f, gs = 0.f;
    for (int b = 0; b < NB; ++b) {
        float csum = 0.f, csq = 0.f, ssum = 0.f, ssq = 0.f, ccnt = 0.f, scnt = 0.f;
        #pragma unroll
        for (int rep = 0; rep < NREP; ++rep) {
            csum += c_part[rep * 2048 + b * NC + c];
            csq  += c_part[rep * 2048 + 1024 + b * NC + c];
            ssum += s_part[rep * 2048 + b * NC + c];
            ssq  += s_part[rep * 2048 + 1024 + b * NC + c];
            ccnt += c_cntp[rep * NB + b];
            scnt += s_cntp[rep * NB + b];
        }
        const float smean = ssum / scnt;
        const float svar  = (ssq - scnt * smean * smean) / (scnt - 1.0f);
        const float sstd  = sqrtf(fmaxf(svar, 0.f)) + 1e-8f;
        if (b == 0) { gm = smean; gs = sstd; }
        else        { gm = 0.9f * gm + 0.1f * smean; gs = 0.9f * gs + 0.1f * sstd; }
        const float cmean = csum / ccnt;
        const float cvar  = (csq - ccnt * cmean * cmean) / (ccnt - 1.0f);
        const float cstd  = sqrtf(fmaxf(cvar, 0.f)) + 1e-8f;
        const float sc = gs / cstd;        // out = sc*x + bi
        scale[b * NC + c] = sc;
        bias [b * NC + c] = gm - sc * cmean;
    }
}

__global__ __launch_bounds__(256) void apply_kernel(
    const float* __restrict__ content, const int* __restrict__ ci, int Nc,
    const float* __restrict__ ws, fvec4* __restrict__ out4)
{
    __shared__ fvec4 s_sc[NB * 17];        // stride-17 pad
    __shared__ fvec4 s_bi[NB * 17];
    const fvec4* scale4 = (const fvec4*)(ws + WS_SCALE);
    const fvec4* bias4  = (const fvec4*)(ws + WS_BIAS);
    for (int i = threadIdx.x; i < NB * 16; i += 256) {
        const int b = i >> 4, c4 = i & 15;
        s_sc[b * 17 + c4] = scale4[i];
        s_bi[b * 17 + c4] = bias4[i];
    }
    __syncthreads();

    const fvec4* feats4 = (const fvec4*)content;
    const int total4 = Nc * 16;
    const int stride = gridDim.x * 256;
    for (int i = blockIdx.x * 256 + threadIdx.x; i < total4; i += stride) {
        const int r  = i >> 4;
        const int c4 = i & 15;
        const int b  = ci[r];
        const fvec4 v  = feats4[i];
        const fvec4 sc = s_sc[b * 17 + c4];
        const fvec4 bi = s_bi[b * 17 + c4];
        fvec4 o;
        o.x = fmaf(sc.x, v.x, bi.x);
        o.y = fmaf(sc.y, v.y, bi.y);
        o.z = fmaf(sc.z, v.z, bi.z);
        o.w = fmaf(sc.w, v.w, bi.w);
        __builtin_nontemporal_store(o, &out4[i]);
    }
}

extern "C" void kernel_launch(void* const* d_in, const int* in_sizes, int n_in,
                              void* d_out, int out_size, void* d_ws, size_t ws_size,
                              hipStream_t stream)
{
    const float* content = (const float*)d_in[0];
    const float* style   = (const float*)d_in[1];
    const int*   ci      = (const int*)d_in[2];
    const int*   si      = (const int*)d_in[3];

    const int Nc = in_sizes[0] / NC;   // 1,000,000
    const int Ns = in_sizes[1] / NC;   //   250,000

    float* ws = (float*)d_ws;
    // ws never re-poisoned between replays: zero accumulators every call.
    (void)hipMemsetAsync(ws, 0, WS_ZERO_FLOATS * sizeof(float), stream);

    reduce_stats<<<CBLKS + SBLKS, 256, 0, stream>>>(content, ci, Nc, style, si, Ns, ws);
    finalize_kernel<<<1, 64, 0, stream>>>(ws);
    apply_kernel<<<2048, 256, 0, stream>>>(content, ci, Nc, ws, (fvec4*)d_out);
}